// Round 5
// baseline (233.155 us; speedup 1.0000x reference)
//
#include <hip/hip_runtime.h>
#include <hip/hip_cooperative_groups.h>
#include <cstdint>

namespace cg = cooperative_groups;

#define NRAD 4096
#define NLID 16384
#define KMIX 8
#define TOPK 10
#define CF   16
#define LOG2PI 1.8378770664093453f
#define GRID_BLOCKS 512

static constexpr unsigned INF_D2 = 62851u;   // > max real d2 (40^2 + 2*175^2 = 62850)

// ---------------------------------------------------------------- helpers
__device__ __forceinline__ void insert_key(unsigned (&t)[TOPK], unsigned key) {
    // t ascending; branch-free exact insert of key into 10 smallest.
#pragma unroll
    for (int i = TOPK - 1; i >= 1; --i) {
        unsigned hi = key > t[i - 1] ? key : t[i - 1];
        t[i] = hi < t[i] ? hi : t[i];
    }
    t[0] = key < t[0] ? key : t[0];
}

__device__ __forceinline__ void merge10(unsigned (&t)[TOPK], int lane,
                                        unsigned& mine, unsigned& first, unsigned& tenth) {
#pragma unroll
    for (int r = 0; r < TOPK; ++r) {
        unsigned v = t[0];
#pragma unroll
        for (int off = 32; off >= 1; off >>= 1) {
            unsigned o = __shfl_xor(v, off, 64);
            v = o < v ? o : v;
        }
        if (t[0] == v) {                       // unique keys -> exactly one popper
#pragma unroll
            for (int i = 0; i < TOPK - 1; ++i) t[i] = t[i + 1];
            t[TOPK - 1] = 0xFFFFFFFFu;
        }
        if (lane == r) mine = v;
        if (r == 0) first = v;
        if (r == TOPK - 1) tenth = v;
    }
}

__device__ __forceinline__ float waveReduceSum(float v) {
#pragma unroll
    for (int off = 32; off >= 1; off >>= 1) v += __shfl_down(v, off, 64);
    return v;
}

// ---------------------------------------------------------------- phase A
// Pack positions; scatter each lidar into its batch's fixed region via global
// atomic cursor. Scatter order nondeterministic == fine (top-k order-indep).
__device__ __forceinline__ void phaseA(const int* __restrict__ lidar_indices,
                                       unsigned* __restrict__ packed_full,
                                       uint2* __restrict__ compacted,
                                       int* __restrict__ cursor, int nblocks) {
    int tid = threadIdx.x, lane = tid & 63;
    for (int base = blockIdx.x * 256; base < NLID; base += nblocks * 256) {
        int i = base + tid;
        int4 li = ((const int4*)lidar_indices)[i];
        int b = li.x;
        unsigned pos = ((unsigned)li.y << 16) | ((unsigned)li.z << 8) | (unsigned)li.w;
        packed_full[i] = ((unsigned)b << 22) | pos;
#pragma unroll
        for (int b2 = 0; b2 < 4; ++b2) {
            unsigned long long mask = __ballot(b == b2);
            if (b == b2) {
                int leader = __ffsll(mask) - 1;
                int off = (int)__popcll(mask & ((1ull << lane) - 1ull));
                int s = 0;
                if (lane == leader) s = atomicAdd(&cursor[b2], (int)__popcll(mask));
                s = __shfl(s, leader, 64);
                compacted[b2 * NLID + s + off] = make_uint2(pos, (unsigned)i);
            }
        }
    }
}

// ---------------------------------------------------------------- phase B/C/D
// One wave per radar row (grid-strided): top-10 NN scan over same-batch
// candidates, then lanes 0..9 compute MDN/occ/int in-wave; block partials +
// done-counter; last block finalizes the scalar loss.
__device__ __forceinline__ void phaseBCD(
        const float* __restrict__ mu_off, const float* __restrict__ log_sig_off,
        const float* __restrict__ mu_int, const float* __restrict__ occ_logit,
        const float* __restrict__ mix_logit, const float* __restrict__ lidar_features,
        const int* __restrict__ radar_indices, const int* __restrict__ lidar_indices,
        const uint2* __restrict__ compacted, const unsigned* __restrict__ packed_full,
        const int* __restrict__ cursor, float4* __restrict__ partials,
        unsigned* __restrict__ dctr, float* __restrict__ out, int nblocks) {
    int tid = threadIdx.x, lane = tid & 63, wid = tid >> 6;
    float lp = 0.f, ip = 0.f, oc = 0.f, mc = 0.f;

    for (int row = blockIdx.x * 4 + wid; row < NRAD; row += nblocks * 4) {
        int4 ri = ((const int4*)radar_indices)[row];
        int rb = ri.x, rz = ri.y, ry = ri.z, rx = ri.w;
        int c_cnt = cursor[rb];

        unsigned t[TOPK];
#pragma unroll
        for (int i = 0; i < TOPK; ++i) t[i] = 0xFFFFFFFFu;

        const uint4* src = (const uint4*)(compacted + rb * NLID);
        int iters = (c_cnt + 127) >> 7;
        uint4 q = src[lane];
        for (int it = 0; it < iters; ++it) {
            uint4 qn = q;
            if (it + 1 < iters) qn = src[(it + 1) * 64 + lane];   // prefetch next
            int c0 = (it * 64 + lane) * 2;
            {
                int dz = (int)((q.x >> 16) & 63u)  - rz;
                int dy = (int)((q.x >> 8)  & 255u) - ry;
                int dx = (int)(q.x & 255u)         - rx;
                unsigned d2 = (unsigned)(dz * dz + dy * dy + dx * dx);
                unsigned key = (c0 < c_cnt) ? ((d2 << 14) | q.y) : 0xFFFFFFFFu;
                if (key < t[TOPK - 1]) insert_key(t, key);
            }
            {
                int dz = (int)((q.z >> 16) & 63u)  - rz;
                int dy = (int)((q.z >> 8)  & 255u) - ry;
                int dx = (int)(q.z & 255u)         - rx;
                unsigned d2 = (unsigned)(dz * dz + dy * dy + dx * dx);
                unsigned key = (c0 + 1 < c_cnt) ? ((d2 << 14) | q.w) : 0xFFFFFFFFu;
                if (key < t[TOPK - 1]) insert_key(t, key);
            }
            q = qn;
        }

        unsigned mine = 0, first = 0, tenth = 0;
        merge10(t, lane, mine, first, tenth);
        bool matched = true;

        if (tenth == 0xFFFFFFFFu) {
            // Degenerate row (<10 same-batch lidar): exact full scan w/ INF keys.
#pragma unroll
            for (int i = 0; i < TOPK; ++i) t[i] = 0xFFFFFFFFu;
            for (int it = 0; it < NLID / 256; ++it) {
                uint4 p4 = ((const uint4*)packed_full)[it * 64 + lane];
                unsigned base = it * 256 + lane * 4;
                unsigned ps[4] = {p4.x, p4.y, p4.z, p4.w};
#pragma unroll
                for (int j = 0; j < 4; ++j) {
                    unsigned p = ps[j];
                    int b  = (int)(p >> 22);
                    int dz = (int)((p >> 16) & 63u)  - rz;
                    int dy = (int)((p >> 8)  & 255u) - ry;
                    int dx = (int)(p & 255u)         - rx;
                    unsigned d2 = (unsigned)(dz * dz + dy * dy + dx * dx);
                    unsigned hi = (b == rb) ? d2 : INF_D2;
                    insert_key(t, (hi << 14) | (base + j));
                }
            }
            merge10(t, lane, mine, first, tenth);
            matched = first < (INF_D2 << 14);
        }

        // ---- per-wave MDN/occ/int: lanes 0..9 handle (row, lane)
        float mf = matched ? 1.f : 0.f;
        if (lane < TOPK) {
            int nni = (int)(mine & 0x3FFFu);
            int4 ll = ((const int4*)lidar_indices)[nni];
            float y0 = mf * (float)(ll.w - rx);
            float y1 = mf * (float)(ll.z - ry);
            float y2 = mf * (float)(ll.y - rz);

            float mix[KMIX];
            float mmax = -1e30f;
#pragma unroll
            for (int k = 0; k < KMIX; ++k) {
                mix[k] = mix_logit[row * KMIX + k];
                mmax = fmaxf(mmax, mix[k]);
            }
            float msum = 0.f;
#pragma unroll
            for (int k = 0; k < KMIX; ++k) msum += __expf(mix[k] - mmax);
            float logZ = mmax + __logf(msum);

            float lpost[KMIX];
            float pmax = -1e30f;
#pragma unroll
            for (int k = 0; k < KMIX; ++k) {
                int bidx = (row * KMIX + k) * 3;
                float mu0 = mu_off[bidx + 0], mu1 = mu_off[bidx + 1], mu2 = mu_off[bidx + 2];
                float l0 = log_sig_off[bidx + 0], l1 = log_sig_off[bidx + 1], l2 = log_sig_off[bidx + 2];
                float s0 = __expf(2.f * l0) + 1e-12f;
                float s1 = __expf(2.f * l1) + 1e-12f;
                float s2 = __expf(2.f * l2) + 1e-12f;
                float d0 = y0 - mu0, d1 = y1 - mu1, d2v = y2 - mu2;
                float qq = d0 * d0 / s0 + d1 * d1 / s1 + d2v * d2v / s2
                         + 2.f * (l0 + l1 + l2) + 3.f * LOG2PI;
                lpost[k] = -0.5f * qq + (mix[k] - logZ);
                pmax = fmaxf(pmax, lpost[k]);
            }
            float ex[KMIX];
            float se = 0.f;
#pragma unroll
            for (int k = 0; k < KMIX; ++k) { ex[k] = __expf(lpost[k] - pmax); se += ex[k]; }
            float logp = pmax + __logf(se);

            float gt = 0.f;
            if (matched) {
                const float* lf = lidar_features + nni * CF;
                gt = 0.25f * (lf[3] + lf[7] + lf[11] + lf[15]);
            }
            float inv_se = 1.f / se;
            float isum = 0.f;
#pragma unroll
            for (int k = 0; k < KMIX; ++k)
                isum += ex[k] * inv_se * fabsf(mu_int[row * KMIX + k] - gt);

            lp += mf * logp;
            ip += mf * isum;
            if (lane == 0) {
                float oa = -1e30f;
#pragma unroll
                for (int k = 0; k < KMIX; ++k) oa = fmaxf(oa, occ_logit[row * KMIX + k]);
                float soft_abs = log1pf(__expf(-fabsf(oa)));
                oc += mf * (soft_abs + fmaxf(-oa, 0.f)) + (1.f - mf) * (soft_abs + fmaxf(oa, 0.f));
                mc += mf;
            }
        }
    }

    // ---- block partial (no atomic contention), done-counter, last-block final
    lp = waveReduceSum(lp); ip = waveReduceSum(ip);
    oc = waveReduceSum(oc); mc = waveReduceSum(mc);
    __shared__ float sA[4], sB[4], sC[4], sD[4];
    __shared__ int isLast;
    if (lane == 0) { sA[wid] = lp; sB[wid] = ip; sC[wid] = oc; sD[wid] = mc; }
    __syncthreads();
    if (tid == 0) {
        partials[blockIdx.x] = make_float4(sA[0] + sA[1] + sA[2] + sA[3],
                                           sB[0] + sB[1] + sB[2] + sB[3],
                                           sC[0] + sC[1] + sC[2] + sC[3],
                                           sD[0] + sD[1] + sD[2] + sD[3]);
        __threadfence();
        unsigned done = atomicAdd(dctr, 1u);
        isLast = (done == (unsigned)(nblocks - 1)) ? 1 : 0;
    }
    __syncthreads();
    if (isLast) {
        __threadfence();   // acquire: other blocks' partials visible
        float a = 0.f, b = 0.f, c = 0.f, d = 0.f;
        for (int i = tid; i < nblocks; i += 256) {
            float4 p = partials[i];
            a += p.x; b += p.y; c += p.z; d += p.w;
        }
        a = waveReduceSum(a); b = waveReduceSum(b);
        c = waveReduceSum(c); d = waveReduceSum(d);
        if (lane == 0) { sA[wid] = a; sB[wid] = b; sC[wid] = c; sD[wid] = d; }
        __syncthreads();
        if (tid == 0) {
            a = sA[0] + sA[1] + sA[2] + sA[3];
            b = sB[0] + sB[1] + sB[2] + sB[3];
            c = sC[0] + sC[1] + sC[2] + sC[3];
            d = sD[0] + sD[1] + sD[2] + sD[3];
            float occ_loss = c / (float)NRAD;
            float mdn_nll  = -a / (d * (float)TOPK);
            float int_loss = b / (d * (float)TOPK * (float)KMIX);
            out[0] = 0.2f * occ_loss + mdn_nll + 0.1f * int_loss;
        }
    }
}

// ---------------------------------------------------------------- kernels
__global__ __launch_bounds__(256) void coop_kernel(
        const float* mu_off, const float* log_sig_off, const float* mu_int,
        const float* occ_logit, const float* mix_logit, const float* lidar_features,
        const int* radar_indices, const int* lidar_indices,
        unsigned* packed_full, uint2* compacted, int* cursor,
        float4* partials, unsigned* dctr, float* out) {
    phaseA(lidar_indices, packed_full, compacted, cursor, GRID_BLOCKS);
    __threadfence();
    cg::this_grid().sync();
    phaseBCD(mu_off, log_sig_off, mu_int, occ_logit, mix_logit, lidar_features,
             radar_indices, lidar_indices, compacted, packed_full, cursor,
             partials, dctr, out, GRID_BLOCKS);
}

__global__ __launch_bounds__(256) void prep_kernel(
        const int* __restrict__ lidar_indices, unsigned* __restrict__ packed_full,
        uint2* __restrict__ compacted, int* __restrict__ cursor) {
    phaseA(lidar_indices, packed_full, compacted, cursor, 64);
}

__global__ __launch_bounds__(256) void main_kernel(
        const float* mu_off, const float* log_sig_off, const float* mu_int,
        const float* occ_logit, const float* mix_logit, const float* lidar_features,
        const int* radar_indices, const int* lidar_indices,
        const unsigned* packed_full, const uint2* compacted, const int* cursor,
        float4* partials, unsigned* dctr, float* out) {
    phaseBCD(mu_off, log_sig_off, mu_int, occ_logit, mix_logit, lidar_features,
             radar_indices, lidar_indices, compacted, packed_full, cursor,
             partials, dctr, out, GRID_BLOCKS);
}

// ---------------------------------------------------------------- launch
extern "C" void kernel_launch(void* const* d_in, const int* in_sizes, int n_in,
                              void* d_out, int out_size, void* d_ws, size_t ws_size,
                              hipStream_t stream) {
    const float* mu_off         = (const float*)d_in[0];
    const float* log_sig_off    = (const float*)d_in[1];
    const float* mu_int         = (const float*)d_in[2];
    const float* occ_logit      = (const float*)d_in[3];
    const float* mix_logit      = (const float*)d_in[4];
    const float* lidar_features = (const float*)d_in[5];
    const int*   radar_indices  = (const int*)d_in[6];
    const int*   lidar_indices  = (const int*)d_in[7];
    float* out = (float*)d_out;

    char* ws = (char*)d_ws;
    unsigned* packed_full = (unsigned*)(ws + 0);         //  64 KB
    uint2*    compacted   = (uint2*)(ws + 65536);        //  4*16384*8 = 512 KB
    int*      cursor      = (int*)(ws + 589824);         //  16 B
    unsigned* dctr        = (unsigned*)(ws + 589840);    //  4 B
    float4*   partials    = (float4*)(ws + 589888);      //  512*16 = 8 KB

    hipMemsetAsync(ws + 589824, 0, 64, stream);          // cursor + dctr

    void* args[] = {
        (void*)&mu_off, (void*)&log_sig_off, (void*)&mu_int, (void*)&occ_logit,
        (void*)&mix_logit, (void*)&lidar_features, (void*)&radar_indices,
        (void*)&lidar_indices, (void*)&packed_full, (void*)&compacted,
        (void*)&cursor, (void*)&partials, (void*)&dctr, (void*)&out
    };
    hipError_t e = hipLaunchCooperativeKernel((const void*)coop_kernel,
                                              dim3(GRID_BLOCKS), dim3(256),
                                              args, 0, stream);
    if (e != hipSuccess) {
        // Fallback: same phases as two ordinary kernels (stream order = barrier).
        hipLaunchKernelGGL(prep_kernel, dim3(64), dim3(256), 0, stream,
                           lidar_indices, packed_full, compacted, cursor);
        hipLaunchKernelGGL(main_kernel, dim3(GRID_BLOCKS), dim3(256), 0, stream,
                           mu_off, log_sig_off, mu_int, occ_logit, mix_logit,
                           lidar_features, radar_indices, lidar_indices,
                           packed_full, compacted, cursor, partials, dctr, out);
    }
}

// Round 6
// 130.413 us; speedup vs baseline: 1.7878x; 1.7878x over previous
//
#include <hip/hip_runtime.h>
#include <cstdint>

#define NRAD 4096
#define NLID 16384
#define KMIX 8
#define TOPK 10
#define CF   16
#define LOG2PI 1.8378770664093453f
#define MAIN_BLOCKS 1024

static constexpr unsigned INF_D2 = 62851u;   // > max real d2 (40^2 + 2*175^2 = 62850)

// ---------------------------------------------------------------- helpers
__device__ __forceinline__ void insert_key(unsigned (&t)[TOPK], unsigned key) {
    // t ascending; branch-free exact insert of key into 10 smallest.
#pragma unroll
    for (int i = TOPK - 1; i >= 1; --i) {
        unsigned hi = key > t[i - 1] ? key : t[i - 1];
        t[i] = hi < t[i] ? hi : t[i];
    }
    t[0] = key < t[0] ? key : t[0];
}

__device__ __forceinline__ void merge10(unsigned (&t)[TOPK], int lane,
                                        unsigned& mine, unsigned& first, unsigned& tenth) {
#pragma unroll
    for (int r = 0; r < TOPK; ++r) {
        unsigned v = t[0];
#pragma unroll
        for (int off = 32; off >= 1; off >>= 1) {
            unsigned o = __shfl_xor(v, off, 64);
            v = o < v ? o : v;
        }
        if (t[0] == v) {                       // unique keys -> exactly one popper
#pragma unroll
            for (int i = 0; i < TOPK - 1; ++i) t[i] = t[i + 1];
            t[TOPK - 1] = 0xFFFFFFFFu;
        }
        if (lane == r) mine = v;
        if (r == 0) first = v;
        if (r == TOPK - 1) tenth = v;
    }
}

__device__ __forceinline__ float waveReduceSum(float v) {
#pragma unroll
    for (int off = 32; off >= 1; off >>= 1) v += __shfl_down(v, off, 64);
    return v;
}

// ---------------------------------------------------------------- prep
// 64 blocks: pack positions; scatter each lidar into its batch's fixed region
// via global atomic cursor. Scatter order nondeterministic == fine (top-k
// selection over keys is scan-order independent).
__global__ __launch_bounds__(256) void prep_kernel(
        const int* __restrict__ lidar_indices,
        unsigned* __restrict__ packed_full,
        uint2* __restrict__ compacted,
        int* __restrict__ cursor) {           // [4], pre-zeroed
    int i = blockIdx.x * 256 + threadIdx.x;
    int lane = threadIdx.x & 63;
    int4 li = ((const int4*)lidar_indices)[i];
    int b = li.x;
    unsigned pos = ((unsigned)li.y << 16) | ((unsigned)li.z << 8) | (unsigned)li.w;
    packed_full[i] = ((unsigned)b << 22) | pos;
#pragma unroll
    for (int b2 = 0; b2 < 4; ++b2) {
        unsigned long long mask = __ballot(b == b2);
        if (b == b2) {
            int leader = __ffsll(mask) - 1;
            int off = (int)__popcll(mask & ((1ull << lane) - 1ull));
            int s = 0;
            if (lane == leader) s = atomicAdd(&cursor[b2], (int)__popcll(mask));
            s = __shfl(s, leader, 64);
            compacted[b2 * NLID + s + off] = make_uint2(pos, (unsigned)i);
        }
    }
}

// ---------------------------------------------------------------- main
// 1024 blocks x 4 waves; one radar row per wave. Top-10 NN over same-batch
// compacted candidates (2-deep prefetch, garbage masked by c_cnt), then
// lanes 0..9 compute MDN/occ/int in-wave. Block partials + done-counter;
// last block finalizes the scalar loss.
__global__ __launch_bounds__(256) void main_kernel(
        const float* __restrict__ mu_off, const float* __restrict__ log_sig_off,
        const float* __restrict__ mu_int, const float* __restrict__ occ_logit,
        const float* __restrict__ mix_logit, const float* __restrict__ lidar_features,
        const int* __restrict__ radar_indices, const int* __restrict__ lidar_indices,
        const uint2* __restrict__ compacted, const unsigned* __restrict__ packed_full,
        const int* __restrict__ cursor, float4* __restrict__ partials,
        unsigned* __restrict__ dctr, float* __restrict__ out) {
    int tid = threadIdx.x, lane = tid & 63, wid = tid >> 6;
    int row = blockIdx.x * 4 + wid;

    int4 ri = ((const int4*)radar_indices)[row];
    int rb = ri.x, rz = ri.y, ry = ri.z, rx = ri.w;
    int c_cnt = cursor[rb];

    unsigned t[TOPK];
#pragma unroll
    for (int i = 0; i < TOPK; ++i) t[i] = 0xFFFFFFFFu;

    // Region rb*NLID..+16384 slots is always allocated: unguarded prefetch up to
    // iters+1 stays in-bounds (max iters=128 -> offset 130*64 < 16384 uint2).
    const uint4* src = (const uint4*)(compacted + rb * NLID);
    int iters = (c_cnt + 127) >> 7;
    uint4 q0 = src[lane];
    uint4 q1 = src[64 + lane];
    for (int it = 0; it < iters; ++it) {
        uint4 qn = src[(it + 2) * 64 + lane];   // 2-deep pipeline (masked later)
        int c0 = (it * 64 + lane) * 2;
        {
            int dz = (int)((q0.x >> 16) & 63u)  - rz;
            int dy = (int)((q0.x >> 8)  & 255u) - ry;
            int dx = (int)(q0.x & 255u)         - rx;
            unsigned d2 = (unsigned)(dz * dz + dy * dy + dx * dx);
            unsigned key = (c0 < c_cnt) ? ((d2 << 14) | q0.y) : 0xFFFFFFFFu;
            if (key < t[TOPK - 1]) insert_key(t, key);
        }
        {
            int dz = (int)((q0.z >> 16) & 63u)  - rz;
            int dy = (int)((q0.z >> 8)  & 255u) - ry;
            int dx = (int)(q0.z & 255u)         - rx;
            unsigned d2 = (unsigned)(dz * dz + dy * dy + dx * dx);
            unsigned key = (c0 + 1 < c_cnt) ? ((d2 << 14) | q0.w) : 0xFFFFFFFFu;
            if (key < t[TOPK - 1]) insert_key(t, key);
        }
        q0 = q1; q1 = qn;
    }

    unsigned mine = 0, first = 0, tenth = 0;
    merge10(t, lane, mine, first, tenth);
    bool matched = true;

    if (tenth == 0xFFFFFFFFu) {
        // Degenerate row (<10 same-batch lidar): exact full scan w/ INF keys.
#pragma unroll
        for (int i = 0; i < TOPK; ++i) t[i] = 0xFFFFFFFFu;
        for (int it = 0; it < NLID / 256; ++it) {
            uint4 p4 = ((const uint4*)packed_full)[it * 64 + lane];
            unsigned base = it * 256 + lane * 4;
            unsigned ps[4] = {p4.x, p4.y, p4.z, p4.w};
#pragma unroll
            for (int j = 0; j < 4; ++j) {
                unsigned p = ps[j];
                int b  = (int)(p >> 22);
                int dz = (int)((p >> 16) & 63u)  - rz;
                int dy = (int)((p >> 8)  & 255u) - ry;
                int dx = (int)(p & 255u)         - rx;
                unsigned d2 = (unsigned)(dz * dz + dy * dy + dx * dx);
                unsigned hi = (b == rb) ? d2 : INF_D2;
                insert_key(t, (hi << 14) | (base + j));
            }
        }
        merge10(t, lane, mine, first, tenth);
        matched = first < (INF_D2 << 14);
    }

    // ---- per-wave MDN/occ/int: lanes 0..9 handle (row, lane); loads broadcast
    float mf = matched ? 1.f : 0.f;
    float lp = 0.f, ip = 0.f, oc = 0.f, mc = 0.f;
    if (lane < TOPK) {
        int nni = (int)(mine & 0x3FFFu);
        int4 ll = ((const int4*)lidar_indices)[nni];
        float y0 = mf * (float)(ll.w - rx);
        float y1 = mf * (float)(ll.z - ry);
        float y2 = mf * (float)(ll.y - rz);

        float mix[KMIX];
        float mmax = -1e30f;
#pragma unroll
        for (int k = 0; k < KMIX; ++k) {
            mix[k] = mix_logit[row * KMIX + k];
            mmax = fmaxf(mmax, mix[k]);
        }
        float msum = 0.f;
#pragma unroll
        for (int k = 0; k < KMIX; ++k) msum += __expf(mix[k] - mmax);
        float logZ = mmax + __logf(msum);

        float lpost[KMIX];
        float pmax = -1e30f;
#pragma unroll
        for (int k = 0; k < KMIX; ++k) {
            int bidx = (row * KMIX + k) * 3;
            float mu0 = mu_off[bidx + 0], mu1 = mu_off[bidx + 1], mu2 = mu_off[bidx + 2];
            float l0 = log_sig_off[bidx + 0], l1 = log_sig_off[bidx + 1], l2 = log_sig_off[bidx + 2];
            float s0 = __expf(2.f * l0) + 1e-12f;
            float s1 = __expf(2.f * l1) + 1e-12f;
            float s2 = __expf(2.f * l2) + 1e-12f;
            float d0 = y0 - mu0, d1 = y1 - mu1, d2v = y2 - mu2;
            float qq = d0 * d0 / s0 + d1 * d1 / s1 + d2v * d2v / s2
                     + 2.f * (l0 + l1 + l2) + 3.f * LOG2PI;
            lpost[k] = -0.5f * qq + (mix[k] - logZ);
            pmax = fmaxf(pmax, lpost[k]);
        }
        float ex[KMIX];
        float se = 0.f;
#pragma unroll
        for (int k = 0; k < KMIX; ++k) { ex[k] = __expf(lpost[k] - pmax); se += ex[k]; }
        float logp = pmax + __logf(se);

        float gt = 0.f;
        if (matched) {
            const float* lf = lidar_features + nni * CF;
            gt = 0.25f * (lf[3] + lf[7] + lf[11] + lf[15]);
        }
        float inv_se = 1.f / se;
        float isum = 0.f;
#pragma unroll
        for (int k = 0; k < KMIX; ++k)
            isum += ex[k] * inv_se * fabsf(mu_int[row * KMIX + k] - gt);

        lp = mf * logp;
        ip = mf * isum;
        if (lane == 0) {
            float oa = -1e30f;
#pragma unroll
            for (int k = 0; k < KMIX; ++k) oa = fmaxf(oa, occ_logit[row * KMIX + k]);
            float soft_abs = log1pf(__expf(-fabsf(oa)));
            oc = mf * (soft_abs + fmaxf(-oa, 0.f)) + (1.f - mf) * (soft_abs + fmaxf(oa, 0.f));
            mc = mf;
        }
    }

    // ---- block partial, done-counter, last-block finalize
    lp = waveReduceSum(lp); ip = waveReduceSum(ip);
    oc = waveReduceSum(oc); mc = waveReduceSum(mc);
    __shared__ float sA[4], sB[4], sC[4], sD[4];
    __shared__ int isLast;
    if (lane == 0) { sA[wid] = lp; sB[wid] = ip; sC[wid] = oc; sD[wid] = mc; }
    __syncthreads();
    if (tid == 0) {
        partials[blockIdx.x] = make_float4(sA[0] + sA[1] + sA[2] + sA[3],
                                           sB[0] + sB[1] + sB[2] + sB[3],
                                           sC[0] + sC[1] + sC[2] + sC[3],
                                           sD[0] + sD[1] + sD[2] + sD[3]);
        __threadfence();
        unsigned done = atomicAdd(dctr, 1u);
        isLast = (done == (unsigned)(MAIN_BLOCKS - 1)) ? 1 : 0;
    }
    __syncthreads();
    if (isLast) {
        __threadfence();   // acquire: other blocks' partials visible
        float a = 0.f, b = 0.f, c = 0.f, d = 0.f;
        for (int i = tid; i < MAIN_BLOCKS; i += 256) {
            float4 p = partials[i];
            a += p.x; b += p.y; c += p.z; d += p.w;
        }
        a = waveReduceSum(a); b = waveReduceSum(b);
        c = waveReduceSum(c); d = waveReduceSum(d);
        if (lane == 0) { sA[wid] = a; sB[wid] = b; sC[wid] = c; sD[wid] = d; }
        __syncthreads();
        if (tid == 0) {
            a = sA[0] + sA[1] + sA[2] + sA[3];
            b = sB[0] + sB[1] + sB[2] + sB[3];
            c = sC[0] + sC[1] + sC[2] + sC[3];
            d = sD[0] + sD[1] + sD[2] + sD[3];
            float occ_loss = c / (float)NRAD;
            float mdn_nll  = -a / (d * (float)TOPK);
            float int_loss = b / (d * (float)TOPK * (float)KMIX);
            out[0] = 0.2f * occ_loss + mdn_nll + 0.1f * int_loss;
        }
    }
}

// ---------------------------------------------------------------- launch
extern "C" void kernel_launch(void* const* d_in, const int* in_sizes, int n_in,
                              void* d_out, int out_size, void* d_ws, size_t ws_size,
                              hipStream_t stream) {
    const float* mu_off         = (const float*)d_in[0];
    const float* log_sig_off    = (const float*)d_in[1];
    const float* mu_int         = (const float*)d_in[2];
    const float* occ_logit      = (const float*)d_in[3];
    const float* mix_logit      = (const float*)d_in[4];
    const float* lidar_features = (const float*)d_in[5];
    const int*   radar_indices  = (const int*)d_in[6];
    const int*   lidar_indices  = (const int*)d_in[7];
    float* out = (float*)d_out;

    char* ws = (char*)d_ws;
    unsigned* packed_full = (unsigned*)(ws + 0);         //  64 KB
    uint2*    compacted   = (uint2*)(ws + 65536);        //  4*16384*8 = 512 KB
    int*      cursor      = (int*)(ws + 589824);         //  16 B
    unsigned* dctr        = (unsigned*)(ws + 589840);    //  4 B
    float4*   partials    = (float4*)(ws + 589888);      //  1024*16 = 16 KB

    hipMemsetAsync(ws + 589824, 0, 64, stream);          // cursor + dctr

    hipLaunchKernelGGL(prep_kernel, dim3(NLID / 256), dim3(256), 0, stream,
                       lidar_indices, packed_full, compacted, cursor);
    hipLaunchKernelGGL(main_kernel, dim3(MAIN_BLOCKS), dim3(256), 0, stream,
                       mu_off, log_sig_off, mu_int, occ_logit, mix_logit,
                       lidar_features, radar_indices, lidar_indices,
                       compacted, packed_full, cursor, partials, dctr, out);
}